// Round 2
// baseline (3096.946 us; speedup 1.0000x reference)
//
#include <hip/hip_runtime.h>
#include <hip/hip_bf16.h>

// DCNConv pipeline, MI355X round 1: fp32 I/O (reference dtypes are float32 —
// round 0's NaN came from misreading fp32 buffers as bf16).
//
// Shapes: x[8,128,160,160] -> conv3x3 s2 p1 + BN + SiLU -> h[8,256,80,80]
//         h -> conv3x3 s1 p1 (+bias) -> offset[8,18,80,80]
//         deform_conv3x3(h, offset, dconv_w) -> y[8,256,80,80]
//         BN + SiLU -> out (fp32)
//
// Internal: h stored bf16 (halves re-read traffic; ~0.4% rms noise, threshold
// is 2% of max|ref|). Accumulation fp32 everywhere.
// Workspace layout (32.3 MB):
//   [0)            h bf16   8*256*6400 elems = 26,214,400 B
//   [26,214,400)   offset fp32 8*18*6400    =  3,686,400 B
//   [29,900,800)   wT fp32 [9][256c][256oc] =  2,359,296 B

typedef __hip_bfloat16 bf16;

#define EPSBN 1e-5f

__device__ __forceinline__ float bf2f(bf16 x){ return __bfloat162float(x); }
__device__ __forceinline__ float silu_(float x){ return x / (1.f + __expf(-x)); }

// ---------------------------------------------------------------------------
// K0: transpose dconv_w [256oc][256c][9k] (fp32) -> wT [9k][256c][256oc] fp32
// so the deform GEMM reads weights coalesced (float4) along oc.
__global__ __launch_bounds__(256) void k_wt(const float* __restrict__ w, float* __restrict__ wT)
{
    int idx = blockIdx.x * 256 + threadIdx.x;      // 589,824 total
    if (idx >= 9 * 256 * 256) return;
    int oc   = idx & 255;
    int rest = idx >> 8;
    int c    = rest & 255;
    int k    = rest >> 8;
    wT[idx] = w[(oc * 256 + c) * 9 + k];
}

// ---------------------------------------------------------------------------
// K1: conv1 (3x3, stride 2, pad 1) + BN1 + SiLU.
// Thread = 4 output channels x 4 spatial positions (16 accums).
// Block: 256 threads -> 1024 consecutive flattened positions; grid.y = 64 oc-groups.
// Weights for the block's 4 ocs staged in LDS as fp32 [c][tap][4].
// Border via clamped offset + float mask (branchless). stride2/pad1 on 160:
// max ih = 159 so only the >= 0 side needs masking.
__global__ __launch_bounds__(256) void k_conv1(
    const float* __restrict__ x, const float* __restrict__ w,
    const float* __restrict__ g, const float* __restrict__ bb,
    const float* __restrict__ mm, const float* __restrict__ vv,
    bf16* __restrict__ h)
{
    __shared__ float ws_[128 * 9 * 4];            // 18,432 B
    const int tid = threadIdx.x;
    const int oc0 = blockIdx.y * 4;

    for (int i = tid; i < 128 * 9 * 4; i += 256){
        int j = i & 3; int r = i >> 2; int tap = r % 9; int c = r / 9;
        ws_[i] = w[((oc0 + j) * 128 + c) * 9 + tap];
    }
    __syncthreads();

    int   ofs[4][9];
    float msk[4][9];
    int   pixv[4], bv[4];
    #pragma unroll
    for (int p = 0; p < 4; p++){
        int pos = blockIdx.x * 1024 + tid + p * 256;   // grid.x = 50 covers 51,200 exactly
        int b   = pos / 6400;
        int pix = pos % 6400;
        int oh  = pix / 80, ow = pix % 80;
        bv[p] = b; pixv[p] = pix;
        #pragma unroll
        for (int tap = 0; tap < 9; tap++){
            int kh = tap / 3, kw = tap % 3;
            int ih = 2 * oh + kh - 1;
            int iw = 2 * ow + kw - 1;
            bool val = (ih >= 0) && (iw >= 0);
            ofs[p][tap] = b * (128 * 25600) + (ih < 0 ? 0 : ih) * 160 + (iw < 0 ? 0 : iw);
            msk[p][tap] = val ? 1.f : 0.f;
        }
    }

    float acc[4][4];
    #pragma unroll
    for (int p = 0; p < 4; p++)
        #pragma unroll
        for (int j = 0; j < 4; j++) acc[p][j] = 0.f;

    for (int c = 0; c < 128; c++){
        const int xc = c * 25600;
        const float* wrow = &ws_[c * 36];
        #pragma unroll
        for (int tap = 0; tap < 9; tap++){
            float w0 = wrow[tap*4+0], w1 = wrow[tap*4+1], w2 = wrow[tap*4+2], w3 = wrow[tap*4+3];
            #pragma unroll
            for (int p = 0; p < 4; p++){
                float xv = x[ofs[p][tap] + xc] * msk[p][tap];
                acc[p][0] += xv * w0; acc[p][1] += xv * w1;
                acc[p][2] += xv * w2; acc[p][3] += xv * w3;
            }
        }
    }

    #pragma unroll
    for (int j = 0; j < 4; j++){
        int oc = oc0 + j;
        float sc = g[oc] * rsqrtf(vv[oc] + EPSBN);
        float sh = bb[oc] - mm[oc] * sc;
        #pragma unroll
        for (int p = 0; p < 4; p++){
            float y = acc[p][j] * sc + sh;
            h[(bv[p] * 256 + oc) * 6400 + pixv[p]] = __float2bfloat16(silu_(y));
        }
    }
}

// ---------------------------------------------------------------------------
// K2: offset conv (3x3, stride 1, pad 1, +bias): h[8,256,80,80] -> off[8,18,80,80] fp32.
// 6400 px per (b,oc) / 256 = 25 blocks -> each block has exactly one (b,oc);
// that oc's 2304 weights staged in LDS (broadcast reads, conflict-free).
__global__ __launch_bounds__(256) void k_off(
    const bf16* __restrict__ h, const float* __restrict__ w,
    const float* __restrict__ bias, float* __restrict__ off)
{
    __shared__ float ws_[256 * 9];                 // 9,216 B
    const int tid = threadIdx.x;
    const int blk = blockIdx.x;                    // 3600 = 8*18*25
    const int boc = blk / 25;                      // b*18 + oc
    const int oc  = boc % 18;
    const int b   = boc / 18;
    const int pix = (blk % 25) * 256 + tid;

    for (int i = tid; i < 2304; i += 256) ws_[i] = w[oc * 2304 + i];
    __syncthreads();

    const int oh = pix / 80, ow = pix % 80;
    int ofs[9]; float msk[9];
    #pragma unroll
    for (int tap = 0; tap < 9; tap++){
        int kh = tap / 3, kw = tap % 3;
        int ih = oh + kh - 1, iw = ow + kw - 1;
        bool val = (ih >= 0) && (ih < 80) && (iw >= 0) && (iw < 80);
        int ihc = min(max(ih, 0), 79), iwc = min(max(iw, 0), 79);
        ofs[tap] = ihc * 80 + iwc;
        msk[tap] = val ? 1.f : 0.f;
    }

    const bf16* hb = h + b * (256 * 6400);
    float acc = bias[oc];
    for (int c = 0; c < 256; c++){
        const bf16*  hc = hb + c * 6400;
        const float* wc = &ws_[c * 9];
        #pragma unroll
        for (int tap = 0; tap < 9; tap++){
            acc += bf2f(hc[ofs[tap]]) * msk[tap] * wc[tap];
        }
    }
    off[boc * 6400 + pix] = acc;
}

// ---------------------------------------------------------------------------
// K3: deformable conv 3x3 + BN2 + SiLU.
// Block = 32 consecutive pixels of one batch image (1600 blocks).
// Stage A: per (pixel,tap) bilinear corner idx (clamped) + weights (validity
//          folded to 0) in LDS once.
// Per tap k: build samp[256c][32t] fp32 in LDS (4 gathered bf16 loads each),
// then register-blocked GEMM: thread owns 4 oc x 8 t; within a wave the samp
// reads are wave-uniform (LDS broadcast, conflict-free) and the wT reads are
// float4-coalesced along oc (that's why K0 transposed the weights).
__global__ __launch_bounds__(256) void k_dconv(
    const bf16* __restrict__ h, const float* __restrict__ off,
    const float* __restrict__ wT,
    const float* __restrict__ g, const float* __restrict__ bb,
    const float* __restrict__ mm, const float* __restrict__ vv,
    float* __restrict__ out)
{
    __shared__ int   sidx[288 * 4];                // 4,608 B
    __shared__ float swt [288 * 4];                // 4,608 B
    __shared__ float samp[256 * 32];               // 32,768 B
    const int tid  = threadIdx.x;
    const int b    = blockIdx.x / 200;
    const int pix0 = (blockIdx.x % 200) * 32;

    for (int e = tid; e < 288; e += 256){
        int t = e & 31, k = e >> 5;                // e = k*32 + t
        int pix = pix0 + t;
        int oh = pix / 80, ow = pix % 80;
        int kh = k / 3, kw = k % 3;
        float oy = off[(b * 18 + 2 * k    ) * 6400 + pix];
        float ox = off[(b * 18 + 2 * k + 1) * 6400 + pix];
        float py = (float)(oh + kh - 1) + oy;
        float px = (float)(ow + kw - 1) + ox;
        float y0f = floorf(py), x0f = floorf(px);
        float wy1 = py - y0f,  wx1 = px - x0f;
        int y0 = (int)y0f, x0 = (int)x0f;
        #pragma unroll
        for (int cy = 0; cy < 2; cy++){
            int   yy = y0 + cy;
            float wy = cy ? wy1 : 1.f - wy1;
            bool  vy = (yy >= 0) && (yy < 80);
            int   yc = min(max(yy, 0), 79);
            #pragma unroll
            for (int cx = 0; cx < 2; cx++){
                int   xx = x0 + cx;
                float wx = cx ? wx1 : 1.f - wx1;
                bool  vx = (xx >= 0) && (xx < 80);
                int   xc = min(max(xx, 0), 79);
                int ci = cy * 2 + cx;
                sidx[e * 4 + ci] = yc * 80 + xc;
                swt [e * 4 + ci] = (vy && vx) ? wy * wx : 0.f;
            }
        }
    }

    float acc[4][8];
    #pragma unroll
    for (int j = 0; j < 4; j++)
        #pragma unroll
        for (int i = 0; i < 8; i++) acc[j][i] = 0.f;

    const int oc0 = (tid & 63) * 4;                // wave lanes cover oc 0..255 in quads
    const int t0  = (tid >> 6) * 8;                // wave w owns t [8w, 8w+8)
    const bf16* hb = h + b * (256 * 6400);

    for (int k = 0; k < 9; k++){
        __syncthreads();                           // guards stage A (k=0) and prev GEMM readers
        for (int i = tid; i < 8192; i += 256){
            int t = i & 31, c = i >> 5;
            int e = k * 32 + t;
            const int*   ip = &sidx[e * 4];
            const float* wp = &swt [e * 4];
            const bf16*  hc = hb + c * 6400;
            float s = wp[0] * bf2f(hc[ip[0]]) + wp[1] * bf2f(hc[ip[1]])
                    + wp[2] * bf2f(hc[ip[2]]) + wp[3] * bf2f(hc[ip[3]]);
            samp[c * 32 + t] = s;
        }
        __syncthreads();

        const float* wk = wT + k * (256 * 256);
        for (int c = 0; c < 256; c++){
            float4 wv = *reinterpret_cast<const float4*>(wk + c * 256 + oc0);     // 16B coalesced
            const float4* sp = reinterpret_cast<const float4*>(&samp[c * 32 + t0]); // wave-uniform
            float4 sa = sp[0], sb = sp[1];
            float sv[8] = {sa.x, sa.y, sa.z, sa.w, sb.x, sb.y, sb.z, sb.w};
            #pragma unroll
            for (int i = 0; i < 8; i++){
                acc[0][i] += wv.x * sv[i];
                acc[1][i] += wv.y * sv[i];
                acc[2][i] += wv.z * sv[i];
                acc[3][i] += wv.w * sv[i];
            }
        }
    }

    #pragma unroll
    for (int j = 0; j < 4; j++){
        int oc = oc0 + j;
        float sc = g[oc] * rsqrtf(vv[oc] + EPSBN);
        float sh = bb[oc] - mm[oc] * sc;
        float* op = out + (b * 256 + oc) * 6400 + pix0 + t0;
        #pragma unroll
        for (int i = 0; i < 8; i++){
            op[i] = silu_(acc[j][i] * sc + sh);
        }
    }
}

// ---------------------------------------------------------------------------
extern "C" void kernel_launch(void* const* d_in, const int* in_sizes, int n_in,
                              void* d_out, int out_size, void* d_ws, size_t ws_size,
                              hipStream_t stream)
{
    (void)in_sizes; (void)n_in; (void)out_size; (void)ws_size;

    const float* x  = (const float*)d_in[0];
    const float* w1 = (const float*)d_in[1];
    const float* g1 = (const float*)d_in[2];
    const float* b1 = (const float*)d_in[3];
    const float* m1 = (const float*)d_in[4];
    const float* v1 = (const float*)d_in[5];
    const float* wo = (const float*)d_in[6];
    const float* bo = (const float*)d_in[7];
    const float* wd = (const float*)d_in[8];
    const float* g2 = (const float*)d_in[9];
    const float* b2 = (const float*)d_in[10];
    const float* m2 = (const float*)d_in[11];
    const float* v2 = (const float*)d_in[12];
    float* outp = (float*)d_out;

    char*  wsb  = (char*)d_ws;
    bf16*  hbuf = (bf16*) wsb;                              // 26,214,400 B
    float* obuf = (float*)(wsb + 26214400);                 //  3,686,400 B
    float* wTb  = (float*)(wsb + 26214400 + 3686400);       //  2,359,296 B

    hipLaunchKernelGGL(k_wt,    dim3(2304),   dim3(256), 0, stream, wd, wTb);
    hipLaunchKernelGGL(k_conv1, dim3(50, 64), dim3(256), 0, stream, x, w1, g1, b1, m1, v1, hbuf);
    hipLaunchKernelGGL(k_off,   dim3(3600),   dim3(256), 0, stream, hbuf, wo, bo, obuf);
    hipLaunchKernelGGL(k_dconv, dim3(1600),   dim3(256), 0, stream, hbuf, obuf, wTb, g2, b2, m2, v2, outp);
}

// Round 3
// 1593.027 us; speedup vs baseline: 1.9441x; 1.9441x over previous
//
#include <hip/hip_runtime.h>
#include <hip/hip_bf16.h>

// DCNConv pipeline, MI355X round 2: conv1 -> bf16 MFMA implicit GEMM.
//
// Shapes: x[8,128,160,160] -> conv3x3 s2 p1 + BN + SiLU -> h[8,256,80,80]
//         h -> conv3x3 s1 p1 (+bias) -> offset[8,18,80,80]
//         deform_conv3x3(h, offset, dconv_w) -> y[8,256,80,80]
//         BN + SiLU -> out (fp32)
//
// conv1 as GEMM: M=256 (oc), N=51200 (b*80*80), K=1152 (c*9 taps),
// mfma_f32_16x16x32_bf16, block = 256oc x 64pos, 36 K-chunks of 32.
// Workspace layout:
//   [0)            h bf16   8*256*6400      = 26,214,400 B
//   [26,214,400)   offset fp32 8*18*6400    =  3,686,400 B
//   [29,900,800)   wT fp32 [9][256c][256oc] =  2,359,296 B   (dconv weights)
//   [32,260,096)   wb bf16 [256oc][1152k]   =    589,824 B   (conv1 weights)

typedef __hip_bfloat16 bf16;
typedef __attribute__((ext_vector_type(8))) short short8;
typedef __attribute__((ext_vector_type(4))) float float4v;

#define EPSBN 1e-5f

__device__ __forceinline__ float bf2f(bf16 x){ return __bfloat162float(x); }
__device__ __forceinline__ float silu_(float x){ return x / (1.f + __expf(-x)); }
__device__ __forceinline__ unsigned short f2bf_bits(float f){
    union { float f; unsigned u; } uf; uf.f = f;
    unsigned r = uf.u + 0x7fff + ((uf.u >> 16) & 1);   // RNE (finite inputs)
    return (unsigned short)(r >> 16);
}

// ---------------------------------------------------------------------------
// K0a: transpose dconv_w [256oc][256c][9k] (fp32) -> wT [9k][256c][256oc] fp32.
__global__ __launch_bounds__(256) void k_wt(const float* __restrict__ w, float* __restrict__ wT)
{
    int idx = blockIdx.x * 256 + threadIdx.x;      // 589,824 total
    if (idx >= 9 * 256 * 256) return;
    int oc   = idx & 255;
    int rest = idx >> 8;
    int c    = rest & 255;
    int k    = rest >> 8;
    wT[idx] = w[(oc * 256 + c) * 9 + k];
}

// K0b: conv1 weights fp32 -> bf16, natural [oc][c][tap] flatten == GEMM [oc][k].
__global__ __launch_bounds__(256) void k_wprep(const float* __restrict__ w, bf16* __restrict__ wb)
{
    int idx = blockIdx.x * 256 + threadIdx.x;      // 294,912 total
    if (idx >= 256 * 1152) return;
    wb[idx] = __float2bfloat16(w[idx]);
}

// ---------------------------------------------------------------------------
// K1: conv1 (3x3 s2 p1) + BN1 + SiLU via MFMA implicit GEMM.
// Block: 256 threads = 4 waves; block tile = 256oc x 64pos; wave w owns oc [64w,64w+64).
// A_lds[256][40] bf16 (row pad 40 shorts = 80 B -> bank stride 20, 2-way = free).
// B_lds[64][40]  bf16, built by im2col gather (thread-fixed k lane = tid&31).
// stride2/pad1 on 160: max ih = 159, only >=0 side needs masking.
__global__ __launch_bounds__(256) void k_conv1(
    const float* __restrict__ x, const bf16* __restrict__ wb,
    const float* __restrict__ g, const float* __restrict__ bb,
    const float* __restrict__ mm, const float* __restrict__ vv,
    bf16* __restrict__ h)
{
    __shared__ short A_lds[256 * 40];              // 20,480 B
    __shared__ short B_lds[64 * 40];               //  5,120 B
    __shared__ float sc_s[256], sh_s[256];         //  2,048 B

    const int tid  = threadIdx.x;
    const int b    = blockIdx.x / 100;             // 800 blocks: 100 per image
    const int pix0 = (blockIdx.x % 100) * 64;
    const float* xb = x + b * (128 * 25600);

    {   // per-oc fused BN constants (tid == oc)
        float scv = g[tid] * rsqrtf(vv[tid] + EPSBN);
        sc_s[tid] = scv;
        sh_s[tid] = bb[tid] - mm[tid] * scv;
    }

    // thread-fixed gather coords: k lane fixed (256 % 32 == 0), 8 positions
    const int k_in = tid & 31;
    const int prow = tid >> 5;                     // 0..7
    int oh8[8], ow8[8];
    #pragma unroll
    for (int p = 0; p < 8; p++){
        int pix = pix0 + prow + p * 8;
        oh8[p] = pix / 80; ow8[p] = pix % 80;
    }

    const int wv   = tid >> 6;                     // wave id 0..3
    const int lane = tid & 63;
    const int lrow = lane & 15;
    const int quad = lane >> 4;

    float4v acc[4][4];
    #pragma unroll
    for (int i = 0; i < 4; i++)
        #pragma unroll
        for (int j = 0; j < 4; j++)
            acc[i][j] = (float4v){0.f, 0.f, 0.f, 0.f};

    for (int kc = 0; kc < 36; kc++){
        const int k0 = kc * 32;
        __syncthreads();                           // prev chunk's frag reads done

        // stage A: 256oc x 32k, thread -> 4 (oc,kq) 16B copies (L2-resident weights)
        #pragma unroll
        for (int p2 = 0; p2 < 4; p2++){
            int idx = p2 * 256 + tid;              // 0..1023
            int oc  = idx >> 2;
            int kq  = idx & 3;
            *reinterpret_cast<uint4*>(&A_lds[oc * 40 + kq * 8]) =
                *reinterpret_cast<const uint4*>(wb + oc * 1152 + k0 + kq * 8);
        }

        // stage B: im2col gather 32k x 64pos
        {
            int kk  = k0 + k_in;
            int c   = kk / 9;
            int tap = kk - 9 * c;
            int kh  = tap / 3 - 1;
            int kw  = tap - 3 * (tap / 3) - 1;
            const float* xc = xb + c * 25600;
            #pragma unroll
            for (int p = 0; p < 8; p++){
                int ih = 2 * oh8[p] + kh;
                int iw = 2 * ow8[p] + kw;
                float v = 0.f;
                if ((ih | iw) >= 0) v = xc[ih * 160 + iw];   // sign-bit test: both >= 0
                B_lds[(prow + p * 8) * 40 + k_in] = (short)f2bf_bits(v);
            }
        }
        __syncthreads();

        // fragments + 16 MFMAs
        short8 af[4], bfv[4];
        #pragma unroll
        for (int i = 0; i < 4; i++){
            int row = wv * 64 + i * 16 + lrow;
            af[i] = *reinterpret_cast<const short8*>(&A_lds[row * 40 + quad * 8]);
        }
        #pragma unroll
        for (int j = 0; j < 4; j++){
            bfv[j] = *reinterpret_cast<const short8*>(&B_lds[(j * 16 + lrow) * 40 + quad * 8]);
        }
        #pragma unroll
        for (int i = 0; i < 4; i++)
            #pragma unroll
            for (int j = 0; j < 4; j++)
                acc[i][j] = __builtin_amdgcn_mfma_f32_16x16x32_bf16(af[i], bfv[j], acc[i][j], 0, 0, 0);
    }

    // epilogue: D col = lane&15 (pos), row = quad*4 + reg (oc); fused BN+SiLU
    #pragma unroll
    for (int i = 0; i < 4; i++){
        #pragma unroll
        for (int r = 0; r < 4; r++){
            int oc = wv * 64 + i * 16 + quad * 4 + r;
            float scv = sc_s[oc], shv = sh_s[oc];
            #pragma unroll
            for (int j = 0; j < 4; j++){
                int pix = pix0 + j * 16 + lrow;
                float y = acc[i][j][r] * scv + shv;
                h[(b * 256 + oc) * 6400 + pix] = __float2bfloat16(silu_(y));
            }
        }
    }
}

// ---------------------------------------------------------------------------
// K2: offset conv (3x3, stride 1, pad 1, +bias): h[8,256,80,80] -> off[8,18,80,80] fp32.
__global__ __launch_bounds__(256) void k_off(
    const bf16* __restrict__ h, const float* __restrict__ w,
    const float* __restrict__ bias, float* __restrict__ off)
{
    __shared__ float ws_[256 * 9];                 // 9,216 B
    const int tid = threadIdx.x;
    const int blk = blockIdx.x;                    // 3600 = 8*18*25
    const int boc = blk / 25;                      // b*18 + oc
    const int oc  = boc % 18;
    const int b   = boc / 18;
    const int pix = (blk % 25) * 256 + tid;

    for (int i = tid; i < 2304; i += 256) ws_[i] = w[oc * 2304 + i];
    __syncthreads();

    const int oh = pix / 80, ow = pix % 80;
    int ofs[9]; float msk[9];
    #pragma unroll
    for (int tap = 0; tap < 9; tap++){
        int kh = tap / 3, kw = tap % 3;
        int ih = oh + kh - 1, iw = ow + kw - 1;
        bool val = (ih >= 0) && (ih < 80) && (iw >= 0) && (iw < 80);
        int ihc = min(max(ih, 0), 79), iwc = min(max(iw, 0), 79);
        ofs[tap] = ihc * 80 + iwc;
        msk[tap] = val ? 1.f : 0.f;
    }

    const bf16* hb = h + b * (256 * 6400);
    float acc = bias[oc];
    for (int c = 0; c < 256; c++){
        const bf16*  hc = hb + c * 6400;
        const float* wc = &ws_[c * 9];
        #pragma unroll
        for (int tap = 0; tap < 9; tap++){
            acc += bf2f(hc[ofs[tap]]) * msk[tap] * wc[tap];
        }
    }
    off[boc * 6400 + pix] = acc;
}

// ---------------------------------------------------------------------------
// K3: deformable conv 3x3 + BN2 + SiLU (scalar GEMM, unchanged this round).
__global__ __launch_bounds__(256) void k_dconv(
    const bf16* __restrict__ h, const float* __restrict__ off,
    const float* __restrict__ wT,
    const float* __restrict__ g, const float* __restrict__ bb,
    const float* __restrict__ mm, const float* __restrict__ vv,
    float* __restrict__ out)
{
    __shared__ int   sidx[288 * 4];                // 4,608 B
    __shared__ float swt [288 * 4];                // 4,608 B
    __shared__ float samp[256 * 32];               // 32,768 B
    const int tid  = threadIdx.x;
    const int b    = blockIdx.x / 200;
    const int pix0 = (blockIdx.x % 200) * 32;

    for (int e = tid; e < 288; e += 256){
        int t = e & 31, k = e >> 5;                // e = k*32 + t
        int pix = pix0 + t;
        int oh = pix / 80, ow = pix % 80;
        int kh = k / 3, kw = k % 3;
        float oy = off[(b * 18 + 2 * k    ) * 6400 + pix];
        float ox = off[(b * 18 + 2 * k + 1) * 6400 + pix];
        float py = (float)(oh + kh - 1) + oy;
        float px = (float)(ow + kw - 1) + ox;
        float y0f = floorf(py), x0f = floorf(px);
        float wy1 = py - y0f,  wx1 = px - x0f;
        int y0 = (int)y0f, x0 = (int)x0f;
        #pragma unroll
        for (int cy = 0; cy < 2; cy++){
            int   yy = y0 + cy;
            float wy = cy ? wy1 : 1.f - wy1;
            bool  vy = (yy >= 0) && (yy < 80);
            int   yc = min(max(yy, 0), 79);
            #pragma unroll
            for (int cx = 0; cx < 2; cx++){
                int   xx = x0 + cx;
                float wx = cx ? wx1 : 1.f - wx1;
                bool  vx = (xx >= 0) && (xx < 80);
                int   xc = min(max(xx, 0), 79);
                int ci = cy * 2 + cx;
                sidx[e * 4 + ci] = yc * 80 + xc;
                swt [e * 4 + ci] = (vy && vx) ? wy * wx : 0.f;
            }
        }
    }

    float acc[4][8];
    #pragma unroll
    for (int j = 0; j < 4; j++)
        #pragma unroll
        for (int i = 0; i < 8; i++) acc[j][i] = 0.f;

    const int oc0 = (tid & 63) * 4;                // wave lanes cover oc 0..255 in quads
    const int t0  = (tid >> 6) * 8;                // wave w owns t [8w, 8w+8)
    const bf16* hb = h + b * (256 * 6400);

    for (int k = 0; k < 9; k++){
        __syncthreads();                           // guards stage A (k=0) and prev GEMM readers
        for (int i = tid; i < 8192; i += 256){
            int t = i & 31, c = i >> 5;
            int e = k * 32 + t;
            const int*   ip = &sidx[e * 4];
            const float* wp = &swt [e * 4];
            const bf16*  hc = hb + c * 6400;
            float s = wp[0] * bf2f(hc[ip[0]]) + wp[1] * bf2f(hc[ip[1]])
                    + wp[2] * bf2f(hc[ip[2]]) + wp[3] * bf2f(hc[ip[3]]);
            samp[c * 32 + t] = s;
        }
        __syncthreads();

        const float* wk = wT + k * (256 * 256);
        for (int c = 0; c < 256; c++){
            float4 wv = *reinterpret_cast<const float4*>(wk + c * 256 + oc0);       // 16B coalesced
            const float4* sp = reinterpret_cast<const float4*>(&samp[c * 32 + t0]); // wave-uniform
            float4 sa = sp[0], sb = sp[1];
            float sv[8] = {sa.x, sa.y, sa.z, sa.w, sb.x, sb.y, sb.z, sb.w};
            #pragma unroll
            for (int i = 0; i < 8; i++){
                acc[0][i] += wv.x * sv[i];
                acc[1][i] += wv.y * sv[i];
                acc[2][i] += wv.z * sv[i];
                acc[3][i] += wv.w * sv[i];
            }
        }
    }

    #pragma unroll
    for (int j = 0; j < 4; j++){
        int oc = oc0 + j;
        float sc = g[oc] * rsqrtf(vv[oc] + EPSBN);
        float sh = bb[oc] - mm[oc] * sc;
        float* op = out + (b * 256 + oc) * 6400 + pix0 + t0;
        #pragma unroll
        for (int i = 0; i < 8; i++){
            op[i] = silu_(acc[j][i] * sc + sh);
        }
    }
}

// ---------------------------------------------------------------------------
extern "C" void kernel_launch(void* const* d_in, const int* in_sizes, int n_in,
                              void* d_out, int out_size, void* d_ws, size_t ws_size,
                              hipStream_t stream)
{
    (void)in_sizes; (void)n_in; (void)out_size; (void)ws_size;

    const float* x  = (const float*)d_in[0];
    const float* w1 = (const float*)d_in[1];
    const float* g1 = (const float*)d_in[2];
    const float* b1 = (const float*)d_in[3];
    const float* m1 = (const float*)d_in[4];
    const float* v1 = (const float*)d_in[5];
    const float* wo = (const float*)d_in[6];
    const float* bo = (const float*)d_in[7];
    const float* wd = (const float*)d_in[8];
    const float* g2 = (const float*)d_in[9];
    const float* b2 = (const float*)d_in[10];
    const float* m2 = (const float*)d_in[11];
    const float* v2 = (const float*)d_in[12];
    float* outp = (float*)d_out;

    char*  wsb  = (char*)d_ws;
    bf16*  hbuf = (bf16*) wsb;                              // 26,214,400 B
    float* obuf = (float*)(wsb + 26214400);                 //  3,686,400 B
    float* wTb  = (float*)(wsb + 26214400 + 3686400);       //  2,359,296 B
    bf16*  wbb  = (bf16*) (wsb + 26214400 + 3686400 + 2359296); // 589,824 B

    hipLaunchKernelGGL(k_wt,    dim3(2304),   dim3(256), 0, stream, wd, wTb);
    hipLaunchKernelGGL(k_wprep, dim3(1152),   dim3(256), 0, stream, w1, wbb);
    hipLaunchKernelGGL(k_conv1, dim3(800),    dim3(256), 0, stream, x, wbb, g1, b1, m1, v1, hbuf);
    hipLaunchKernelGGL(k_off,   dim3(3600),   dim3(256), 0, stream, hbuf, wo, bo, obuf);
    hipLaunchKernelGGL(k_dconv, dim3(1600),   dim3(256), 0, stream, hbuf, obuf, wTb, g2, b2, m2, v2, outp);
}